// Round 1
// baseline (1847.299 us; speedup 1.0000x reference)
//
#include <hip/hip_runtime.h>
#include <hip/hip_bf16.h>

#define NE 8
#define FF 4096
#define HH 2048
#define TT 2048
#define KTOP 4

typedef unsigned short u16;
typedef __attribute__((ext_vector_type(8))) short bf16x8;
typedef __attribute__((ext_vector_type(4))) float f32x4;

__device__ __forceinline__ u16 f2u(float f) {
  __hip_bfloat16 b = __float2bfloat16(f);
  return *reinterpret_cast<u16*>(&b);
}

__device__ __forceinline__ void gld16(void* lds, const void* g) {
  __builtin_amdgcn_global_load_lds(
      (const __attribute__((address_space(1))) void*)g,
      (__attribute__((address_space(3))) void*)lds, 16, 0, 0);
}

// scale[t][e] = sum_k tw[t][k] * (te[t][k]==e)
__global__ void k_scale(const float* __restrict__ tw, const int* __restrict__ te,
                        float* __restrict__ scale) {
  int t = blockIdx.x * blockDim.x + threadIdx.x;
  if (t >= TT) return;
  float w0 = tw[t*KTOP+0], w1 = tw[t*KTOP+1], w2 = tw[t*KTOP+2], w3 = tw[t*KTOP+3];
  int e0 = te[t*KTOP+0], e1 = te[t*KTOP+1], e2 = te[t*KTOP+2], e3 = te[t*KTOP+3];
  #pragma unroll
  for (int e = 0; e < NE; ++e) {
    float s = 0.f;
    s += (e0 == e) ? w0 : 0.f;
    s += (e1 == e) ? w1 : 0.f;
    s += (e2 == e) ? w2 : 0.f;
    s += (e3 == e) ? w3 : 0.f;
    scale[t*NE + e] = s;
  }
}

// vectorized fp32 -> bf16 cast
__global__ void k_cast4(const float4* __restrict__ src, ushort4* __restrict__ dst, int n4) {
  int stride = gridDim.x * blockDim.x;
  for (int i = blockIdx.x * blockDim.x + threadIdx.x; i < n4; i += stride) {
    float4 f = src[i];
    ushort4 o;
    o.x = f2u(f.x); o.y = f2u(f.y); o.z = f2u(f.z); o.w = f2u(f.w);
    dst[i] = o;
  }
}

// w2[e]: [FF][HH] fp32  ->  dst: [HH][FF] bf16 (transposed)
__global__ void k_tcast(const float* __restrict__ src, u16* __restrict__ dst) {
  __shared__ float tile[32][33];
  int h0 = blockIdx.x * 32;
  int f0 = blockIdx.y * 32;
  int tx = threadIdx.x, ty = threadIdx.y;   // (32, 8)
  #pragma unroll
  for (int i = 0; i < 4; ++i)
    tile[ty + i*8][tx] = src[(size_t)(f0 + ty + i*8) * HH + h0 + tx];
  __syncthreads();
  #pragma unroll
  for (int i = 0; i < 4; ++i)
    dst[(size_t)(h0 + ty + i*8) * FF + f0 + tx] = f2u(tile[tx][ty + i*8]);
}

// C[M,N] = A[M,K] @ B[N,K]^T, bf16 in, fp32 acc. 128x128 tile, BK=64, 4 waves.
// MODE 0: store C fp32 (gate)
// MODE 1: h = silu(Gin) * C -> bf16 Hout
// MODE 2: Out (+)= C * Scale[row*8+eIdx]
template<int MODE>
__global__ __launch_bounds__(256)
void k_gemm(const u16* __restrict__ A, const u16* __restrict__ B,
            int K, int N,
            float* __restrict__ Cf,
            const float* __restrict__ Gin, u16* __restrict__ Hout,
            float* __restrict__ Out, const float* __restrict__ Scale,
            int eIdx, int accumulate) {
  __shared__ __align__(16) u16 As[128*64];
  __shared__ __align__(16) u16 Bs[128*64];
  const int tid  = threadIdx.x;
  const int lane = tid & 63;
  const int wave = tid >> 6;
  const int wm = wave >> 1, wn = wave & 1;
  const int rowA0 = blockIdx.y * 128;
  const int rowB0 = blockIdx.x * 128;

  f32x4 acc[4][4];
  #pragma unroll
  for (int m = 0; m < 4; ++m)
    #pragma unroll
    for (int n = 0; n < 4; ++n)
      acc[m][n] = (f32x4){0.f, 0.f, 0.f, 0.f};

  // staging map: chunk c = i*256 + tid  ->  row c>>3, col8 c&7 (64 bf16 = 8 chunks/row)
  const int srow = tid >> 3;
  const int scol = (tid & 7) * 8;
  const u16* Ag = A + (size_t)(rowA0 + srow) * K + scol;
  const u16* Bg = B + (size_t)(rowB0 + srow) * K + scol;
  u16* Al = As + tid * 8;
  u16* Bl = Bs + tid * 8;

  const int lr = lane & 15;
  const int nk = K >> 6;
  for (int kt = 0; kt < nk; ++kt) {
    const int ko = kt * 64;
    #pragma unroll
    for (int i = 0; i < 4; ++i) {
      gld16(Al + i * 256 * 8, Ag + (size_t)(i * 32) * K + ko);
      gld16(Bl + i * 256 * 8, Bg + (size_t)(i * 32) * K + ko);
    }
    __syncthreads();
    #pragma unroll
    for (int ks = 0; ks < 2; ++ks) {
      const int lk = ks * 32 + (lane >> 4) * 8;
      bf16x8 af[4], bfr[4];
      #pragma unroll
      for (int m = 0; m < 4; ++m)
        af[m] = *(const bf16x8*)(As + (wm*64 + m*16 + lr) * 64 + lk);
      #pragma unroll
      for (int n = 0; n < 4; ++n)
        bfr[n] = *(const bf16x8*)(Bs + (wn*64 + n*16 + lr) * 64 + lk);
      #pragma unroll
      for (int m = 0; m < 4; ++m)
        #pragma unroll
        for (int n = 0; n < 4; ++n)
          acc[m][n] = __builtin_amdgcn_mfma_f32_16x16x32_bf16(af[m], bfr[n], acc[m][n], 0, 0, 0);
    }
    __syncthreads();
  }

  // C/D layout (verified m89/m91): col = lane&15, row = (lane>>4)*4 + reg
  const int row0 = rowA0 + wm * 64;
  const int col0 = rowB0 + wn * 64;
  const int lr4 = (lane >> 4) * 4;
  const int lc  = lane & 15;
  #pragma unroll
  for (int m = 0; m < 4; ++m) {
    #pragma unroll
    for (int n = 0; n < 4; ++n) {
      #pragma unroll
      for (int j = 0; j < 4; ++j) {
        int r = row0 + m*16 + lr4 + j;
        int c = col0 + n*16 + lc;
        size_t off = (size_t)r * N + c;
        float v = acc[m][n][j];
        if (MODE == 0) {
          Cf[off] = v;
        } else if (MODE == 1) {
          float g = Gin[off];
          float hh = (g / (1.f + __expf(-g))) * v;   // silu(gate) * up
          Hout[off] = f2u(hh);
        } else {
          float s = Scale[r * NE + eIdx];
          float val = v * s;
          if (accumulate) Out[off] += val;
          else            Out[off] = val;
        }
      }
    }
  }
}

extern "C" void kernel_launch(void* const* d_in, const int* in_sizes, int n_in,
                              void* d_out, int out_size, void* d_ws, size_t ws_size,
                              hipStream_t stream) {
  const float* x  = (const float*)d_in[0];
  // d_in[1] = router weights, unused by reference forward
  const float* tw = (const float*)d_in[2];
  const int*   te = (const int*)d_in[3];
  const float* w1 = (const float*)d_in[4];
  const float* v1 = (const float*)d_in[5];
  const float* w2 = (const float*)d_in[6];
  float* out = (float*)d_out;

  char* p = (char*)d_ws;
  float* scale = (float*)p;      p += (size_t)TT * NE * 4;     // 64 KB
  u16*   xb    = (u16*)p;        p += (size_t)TT * HH * 2;     // 8 MB
  u16*   w1b   = (u16*)p;        p += (size_t)FF * HH * 2;     // 16.75 MB
  u16*   v1b   = (u16*)p;        p += (size_t)FF * HH * 2;
  u16*   w2tb  = (u16*)p;        p += (size_t)FF * HH * 2;
  float* gate  = (float*)p;      p += (size_t)TT * FF * 4;     // 33.5 MB
  u16*   hbuf  = (u16*)p;        p += (size_t)TT * FF * 2;     // 16.75 MB
  // total ~104 MB of ws

  k_scale<<<(TT + 255) / 256, 256, 0, stream>>>(tw, te, scale);
  k_cast4<<<1024, 256, 0, stream>>>((const float4*)x, (ushort4*)xb, TT * HH / 4);

  for (int e = 0; e < NE; ++e) {
    const size_t wo = (size_t)e * FF * HH;
    k_cast4<<<2048, 256, 0, stream>>>((const float4*)(w1 + wo), (ushort4*)w1b, FF * HH / 4);
    k_cast4<<<2048, 256, 0, stream>>>((const float4*)(v1 + wo), (ushort4*)v1b, FF * HH / 4);
    k_tcast<<<dim3(HH / 32, FF / 32), dim3(32, 8), 0, stream>>>(w2 + wo, w2tb);

    // gate = x @ w1[e]^T   (M=TT, N=FF, K=HH)
    k_gemm<0><<<dim3(FF / 128, TT / 128), 256, 0, stream>>>(
        xb, w1b, HH, FF, gate, nullptr, nullptr, nullptr, nullptr, 0, 0);
    // h = silu(gate) * (x @ v1[e]^T)
    k_gemm<1><<<dim3(FF / 128, TT / 128), 256, 0, stream>>>(
        xb, v1b, HH, FF, nullptr, gate, hbuf, nullptr, nullptr, 0, 0);
    // out (+)= (h @ w2[e]) * scale[:,e]   (M=TT, N=HH, K=FF)
    k_gemm<2><<<dim3(HH / 128, TT / 128), 256, 0, stream>>>(
        hbuf, w2tb, FF, HH, nullptr, nullptr, nullptr, out, scale, e, e > 0);
  }
}

// Round 2
// 991.373 us; speedup vs baseline: 1.8634x; 1.8634x over previous
//
#include <hip/hip_runtime.h>
#include <hip/hip_bf16.h>

#define NE 8
#define FF 4096
#define HH 2048
#define TT 2048
#define KTOP 4

typedef unsigned short u16;
typedef __attribute__((ext_vector_type(8))) short bf16x8;
typedef __attribute__((ext_vector_type(4))) float f32x4;

__device__ __forceinline__ u16 f2u(float f) {
  __hip_bfloat16 b = __float2bfloat16(f);
  return *reinterpret_cast<u16*>(&b);
}

__device__ __forceinline__ void gld16(void* lds, const void* g) {
  __builtin_amdgcn_global_load_lds(
      (const __attribute__((address_space(1))) void*)g,
      (__attribute__((address_space(3))) void*)lds, 16, 0, 0);
}

// Per-expert token lists. One block per expert, deterministic order (token asc).
// tok[e][r] = t for the r-th token using expert e; posmap[t][e] = r.
__global__ void k_build(const int* __restrict__ te, int* __restrict__ cnt,
                        int* __restrict__ tok, int* __restrict__ posmap) {
  const int e = blockIdx.x;
  const int tl = threadIdx.x;          // 256 threads, 8 tokens each
  const int base = tl * 8;
  int mem[8];
  int my = 0;
  #pragma unroll
  for (int i = 0; i < 8; ++i) {
    const int t = base + i;
    bool m = false;
    #pragma unroll
    for (int k = 0; k < KTOP; ++k) m |= (te[t * KTOP + k] == e);
    mem[i] = m ? 1 : 0;
    my += mem[i];
  }
  __shared__ int s[256];
  s[tl] = my;
  __syncthreads();
  for (int off = 1; off < 256; off <<= 1) {
    int v = (tl >= off) ? s[tl - off] : 0;
    __syncthreads();
    s[tl] += v;
    __syncthreads();
  }
  int r = s[tl] - my;                  // exclusive prefix
  if (tl == 255) cnt[e] = s[255];
  #pragma unroll
  for (int i = 0; i < 8; ++i) {
    if (mem[i]) {
      const int t = base + i;
      tok[e * TT + r] = t;
      posmap[t * NE + e] = r;
      ++r;
    }
  }
}

// vectorized fp32 -> bf16 cast
__global__ void k_cast4(const float4* __restrict__ src, ushort4* __restrict__ dst, int n4) {
  int stride = gridDim.x * blockDim.x;
  for (int i = blockIdx.x * blockDim.x + threadIdx.x; i < n4; i += stride) {
    float4 f = src[i];
    ushort4 o;
    o.x = f2u(f.x); o.y = f2u(f.y); o.z = f2u(f.z); o.w = f2u(f.w);
    dst[i] = o;
  }
}

// w2[e]: [FF][HH] fp32  ->  [HH][FF] bf16 (transposed), all experts via z
__global__ void k_tcast(const float* __restrict__ w2, u16* __restrict__ dst) {
  const int e = blockIdx.z;
  const float* src = w2 + (size_t)e * FF * HH;
  u16* d = dst + (size_t)e * HH * FF;
  __shared__ float tile[32][33];
  int h0 = blockIdx.x * 32;
  int f0 = blockIdx.y * 32;
  int tx = threadIdx.x, ty = threadIdx.y;   // (32, 8)
  #pragma unroll
  for (int i = 0; i < 4; ++i)
    tile[ty + i*8][tx] = src[(size_t)(f0 + ty + i*8) * HH + h0 + tx];
  __syncthreads();
  #pragma unroll
  for (int i = 0; i < 4; ++i)
    d[(size_t)(h0 + ty + i*8) * FF + f0 + tx] = f2u(tile[tx][ty + i*8]);
}

// gather x rows into compact per-expert panels, zero-pad to 128 multiple.
// grid (TT, NE), 256 threads: one row per block, 8 bf16 (16 B) per thread.
__global__ void k_gather(const u16* __restrict__ xb, const int* __restrict__ tok,
                         const int* __restrict__ cnt, u16* __restrict__ xg) {
  const int e = blockIdx.y;
  const int r = blockIdx.x;
  const int c = cnt[e];
  const int mcap = (c + 127) & ~127;
  if (r >= mcap) return;
  uint4* dst = (uint4*)(xg + ((size_t)e * TT + r) * HH) + threadIdx.x;
  if (r < c) {
    const uint4* src = (const uint4*)(xb + (size_t)tok[e * TT + r] * HH) + threadIdx.x;
    *dst = *src;
  } else {
    *dst = (uint4){0, 0, 0, 0};
  }
}

// Fused gate+up GEMM: h = silu(xg@w1^T) * (xg@v1^T), bf16 out (compact rows).
// 128x128 tile, BK=64, 4 waves, dual-B staging.
__global__ __launch_bounds__(256)
void k_glu(const u16* __restrict__ xg, const u16* __restrict__ w1b,
           const u16* __restrict__ v1b, const int* __restrict__ cnt,
           u16* __restrict__ hc) {
  const int e = blockIdx.z;
  const int mcap = (cnt[e] + 127) & ~127;
  const int rowA0 = blockIdx.y * 128;
  if (rowA0 >= mcap) return;
  const u16* A  = xg  + (size_t)e * TT * HH;
  const u16* B1 = w1b + (size_t)e * FF * HH;
  const u16* B2 = v1b + (size_t)e * FF * HH;
  u16* Hc = hc + (size_t)e * TT * FF;

  __shared__ __align__(16) u16 As[128*64];
  __shared__ __align__(16) u16 B1s[128*64];
  __shared__ __align__(16) u16 B2s[128*64];
  const int tid  = threadIdx.x;
  const int lane = tid & 63;
  const int wave = tid >> 6;
  const int wm = wave >> 1, wn = wave & 1;
  const int rowB0 = blockIdx.x * 128;

  f32x4 ag[4][4], au[4][4];
  #pragma unroll
  for (int m = 0; m < 4; ++m)
    #pragma unroll
    for (int n = 0; n < 4; ++n) {
      ag[m][n] = (f32x4){0.f, 0.f, 0.f, 0.f};
      au[m][n] = (f32x4){0.f, 0.f, 0.f, 0.f};
    }

  const int srow = tid >> 3;
  const int scol = (tid & 7) * 8;
  const u16* Ag  = A  + (size_t)(rowA0 + srow) * HH + scol;
  const u16* B1g = B1 + (size_t)(rowB0 + srow) * HH + scol;
  const u16* B2g = B2 + (size_t)(rowB0 + srow) * HH + scol;
  u16* Al  = As  + tid * 8;
  u16* B1l = B1s + tid * 8;
  u16* B2l = B2s + tid * 8;

  const int lr = lane & 15;
  for (int kt = 0; kt < HH / 64; ++kt) {
    const int ko = kt * 64;
    #pragma unroll
    for (int i = 0; i < 4; ++i) {
      gld16(Al  + i * 2048, Ag  + (size_t)(i * 32) * HH + ko);
      gld16(B1l + i * 2048, B1g + (size_t)(i * 32) * HH + ko);
      gld16(B2l + i * 2048, B2g + (size_t)(i * 32) * HH + ko);
    }
    __syncthreads();
    #pragma unroll
    for (int ks = 0; ks < 2; ++ks) {
      const int lk = ks * 32 + (lane >> 4) * 8;
      bf16x8 af[4], b1f[4], b2f[4];
      #pragma unroll
      for (int m = 0; m < 4; ++m)
        af[m] = *(const bf16x8*)(As + (wm*64 + m*16 + lr) * 64 + lk);
      #pragma unroll
      for (int n = 0; n < 4; ++n) {
        b1f[n] = *(const bf16x8*)(B1s + (wn*64 + n*16 + lr) * 64 + lk);
        b2f[n] = *(const bf16x8*)(B2s + (wn*64 + n*16 + lr) * 64 + lk);
      }
      #pragma unroll
      for (int m = 0; m < 4; ++m)
        #pragma unroll
        for (int n = 0; n < 4; ++n) {
          ag[m][n] = __builtin_amdgcn_mfma_f32_16x16x32_bf16(af[m], b1f[n], ag[m][n], 0, 0, 0);
          au[m][n] = __builtin_amdgcn_mfma_f32_16x16x32_bf16(af[m], b2f[n], au[m][n], 0, 0, 0);
        }
    }
    __syncthreads();
  }

  const int row0 = rowA0 + wm * 64;
  const int col0 = rowB0 + wn * 64;
  const int lr4 = (lane >> 4) * 4;
  const int lc  = lane & 15;
  #pragma unroll
  for (int m = 0; m < 4; ++m)
    #pragma unroll
    for (int n = 0; n < 4; ++n)
      #pragma unroll
      for (int j = 0; j < 4; ++j) {
        int r = row0 + m*16 + lr4 + j;
        int c = col0 + n*16 + lc;
        float g = ag[m][n][j];
        float u = au[m][n][j];
        float hh = (g / (1.f + __expf(-g))) * u;
        Hc[(size_t)r * FF + c] = f2u(hh);
      }
}

// Down GEMM: dcomp[e][r][:] = hc[e][r][:] @ w2t[e]^T (unscaled fp32, compact rows)
__global__ __launch_bounds__(256)
void k_dn(const u16* __restrict__ hc, const u16* __restrict__ w2tb,
          const int* __restrict__ cnt, float* __restrict__ dcomp) {
  const int e = blockIdx.z;
  const int mcap = (cnt[e] + 127) & ~127;
  const int rowA0 = blockIdx.y * 128;
  if (rowA0 >= mcap) return;
  const u16* A = hc   + (size_t)e * TT * FF;   // K = FF
  const u16* B = w2tb + (size_t)e * HH * FF;   // [HH][FF]
  float* D = dcomp + (size_t)e * TT * HH;

  __shared__ __align__(16) u16 As[128*64];
  __shared__ __align__(16) u16 Bs[128*64];
  const int tid  = threadIdx.x;
  const int lane = tid & 63;
  const int wave = tid >> 6;
  const int wm = wave >> 1, wn = wave & 1;
  const int rowB0 = blockIdx.x * 128;

  f32x4 acc[4][4];
  #pragma unroll
  for (int m = 0; m < 4; ++m)
    #pragma unroll
    for (int n = 0; n < 4; ++n)
      acc[m][n] = (f32x4){0.f, 0.f, 0.f, 0.f};

  const int srow = tid >> 3;
  const int scol = (tid & 7) * 8;
  const u16* Ag = A + (size_t)(rowA0 + srow) * FF + scol;
  const u16* Bg = B + (size_t)(rowB0 + srow) * FF + scol;
  u16* Al = As + tid * 8;
  u16* Bl = Bs + tid * 8;

  const int lr = lane & 15;
  for (int kt = 0; kt < FF / 64; ++kt) {
    const int ko = kt * 64;
    #pragma unroll
    for (int i = 0; i < 4; ++i) {
      gld16(Al + i * 2048, Ag + (size_t)(i * 32) * FF + ko);
      gld16(Bl + i * 2048, Bg + (size_t)(i * 32) * FF + ko);
    }
    __syncthreads();
    #pragma unroll
    for (int ks = 0; ks < 2; ++ks) {
      const int lk = ks * 32 + (lane >> 4) * 8;
      bf16x8 af[4], bfr[4];
      #pragma unroll
      for (int m = 0; m < 4; ++m)
        af[m] = *(const bf16x8*)(As + (wm*64 + m*16 + lr) * 64 + lk);
      #pragma unroll
      for (int n = 0; n < 4; ++n)
        bfr[n] = *(const bf16x8*)(Bs + (wn*64 + n*16 + lr) * 64 + lk);
      #pragma unroll
      for (int m = 0; m < 4; ++m)
        #pragma unroll
        for (int n = 0; n < 4; ++n)
          acc[m][n] = __builtin_amdgcn_mfma_f32_16x16x32_bf16(af[m], bfr[n], acc[m][n], 0, 0, 0);
    }
    __syncthreads();
  }

  const int row0 = rowA0 + wm * 64;
  const int col0 = rowB0 + wn * 64;
  const int lr4 = (lane >> 4) * 4;
  const int lc  = lane & 15;
  #pragma unroll
  for (int m = 0; m < 4; ++m)
    #pragma unroll
    for (int n = 0; n < 4; ++n)
      #pragma unroll
      for (int j = 0; j < 4; ++j) {
        int r = row0 + m*16 + lr4 + j;
        int c = col0 + n*16 + lc;
        D[(size_t)r * HH + c] = acc[m][n][j];
      }
}

// out[t][:] = sum_k tw[t][k] * dcomp[te[t][k]][posmap[t][te]][:]
__global__ void k_combine(const float* __restrict__ tw, const int* __restrict__ te,
                          const int* __restrict__ posmap, const float* __restrict__ dcomp,
                          float* __restrict__ out) {
  const int t = blockIdx.x;
  const int c0 = threadIdx.x * 8;      // 256 threads x 8 floats = 2048
  float a[8] = {0.f, 0.f, 0.f, 0.f, 0.f, 0.f, 0.f, 0.f};
  #pragma unroll
  for (int k = 0; k < KTOP; ++k) {
    const int e = te[t * KTOP + k];
    const float w = tw[t * KTOP + k];
    const int r = posmap[t * NE + e];
    const float* row = dcomp + ((size_t)e * TT + r) * HH + c0;
    const float4 p = ((const float4*)row)[0];
    const float4 q = ((const float4*)row)[1];
    a[0] += w * p.x; a[1] += w * p.y; a[2] += w * p.z; a[3] += w * p.w;
    a[4] += w * q.x; a[5] += w * q.y; a[6] += w * q.z; a[7] += w * q.w;
  }
  float* o = out + (size_t)t * HH + c0;
  ((float4*)o)[0] = (float4){a[0], a[1], a[2], a[3]};
  ((float4*)o)[1] = (float4){a[4], a[5], a[6], a[7]};
}

extern "C" void kernel_launch(void* const* d_in, const int* in_sizes, int n_in,
                              void* d_out, int out_size, void* d_ws, size_t ws_size,
                              hipStream_t stream) {
  const float* x  = (const float*)d_in[0];
  const float* tw = (const float*)d_in[2];
  const int*   te = (const int*)d_in[3];
  const float* w1 = (const float*)d_in[4];
  const float* v1 = (const float*)d_in[5];
  const float* w2 = (const float*)d_in[6];
  float* out = (float*)d_out;

  char* p = (char*)d_ws;
  int*   cnt    = (int*)p;   p += 256;
  int*   tok    = (int*)p;   p += (size_t)NE * TT * 4;            // 64 KB
  int*   posmap = (int*)p;   p += (size_t)TT * NE * 4;            // 64 KB
  u16*   xb     = (u16*)p;   p += (size_t)TT * HH * 2;            // 8 MB
  u16*   xg     = (u16*)p;   p += (size_t)NE * TT * HH * 2;       // 64 MB
  u16*   w1b    = (u16*)p;   p += (size_t)NE * FF * HH * 2;       // 134 MB
  u16*   v1b    = (u16*)p;   p += (size_t)NE * FF * HH * 2;       // 134 MB
  u16*   w2tb   = (u16*)p;   p += (size_t)NE * HH * FF * 2;       // 134 MB
  u16*   hc     = (u16*)p;   p += (size_t)NE * TT * FF * 2;       // 134 MB
  float* dcomp  = (float*)p; p += (size_t)NE * TT * HH * 4;       // 134 MB
  // total ~744 MB (ws is 1 GiB per harness poison-fill traffic)

  k_build<<<NE, 256, 0, stream>>>(te, cnt, tok, posmap);
  k_cast4<<<1024, 256, 0, stream>>>((const float4*)x, (ushort4*)xb, TT * HH / 4);
  k_cast4<<<4096, 256, 0, stream>>>((const float4*)w1, (ushort4*)w1b, NE * FF * HH / 4);
  k_cast4<<<4096, 256, 0, stream>>>((const float4*)v1, (ushort4*)v1b, NE * FF * HH / 4);
  k_tcast<<<dim3(HH / 32, FF / 32, NE), dim3(32, 8), 0, stream>>>(w2, w2tb);
  k_gather<<<dim3(TT, NE), 256, 0, stream>>>(xb, tok, cnt, xg);

  k_glu<<<dim3(FF / 128, TT / 128, NE), 256, 0, stream>>>(xg, w1b, v1b, cnt, hc);
  k_dn<<<dim3(HH / 128, TT / 128, NE), 256, 0, stream>>>(hc, w2tb, cnt, dcomp);
  k_combine<<<TT, 256, 0, stream>>>(tw, te, posmap, dcomp, out);
}

// Round 3
// 693.782 us; speedup vs baseline: 2.6626x; 1.4289x over previous
//
#include <hip/hip_runtime.h>
#include <hip/hip_bf16.h>

#define NE 8
#define FF 4096
#define HH 2048
#define TT 2048
#define KTOP 4

typedef unsigned short u16;
typedef __attribute__((ext_vector_type(8))) short bf16x8;
typedef __attribute__((ext_vector_type(4))) float f32x4;

__device__ __forceinline__ u16 f2u(float f) {
  __hip_bfloat16 b = __float2bfloat16(f);
  return *reinterpret_cast<u16*>(&b);
}

__device__ __forceinline__ void gld16(void* lds, const void* g) {
  __builtin_amdgcn_global_load_lds(
      (const __attribute__((address_space(1))) void*)g,
      (__attribute__((address_space(3))) void*)lds, 16, 0, 0);
}

// Per-expert token lists, deterministic (token ascending).
__global__ void k_build(const int* __restrict__ te, int* __restrict__ cnt,
                        int* __restrict__ tok, int* __restrict__ posmap) {
  const int e = blockIdx.x;
  const int tl = threadIdx.x;          // 256 threads, 8 tokens each
  const int base = tl * 8;
  int mem[8];
  int my = 0;
  #pragma unroll
  for (int i = 0; i < 8; ++i) {
    const int t = base + i;
    bool m = false;
    #pragma unroll
    for (int k = 0; k < KTOP; ++k) m |= (te[t * KTOP + k] == e);
    mem[i] = m ? 1 : 0;
    my += mem[i];
  }
  __shared__ int s[256];
  s[tl] = my;
  __syncthreads();
  for (int off = 1; off < 256; off <<= 1) {
    int v = (tl >= off) ? s[tl - off] : 0;
    __syncthreads();
    s[tl] += v;
    __syncthreads();
  }
  int r = s[tl] - my;
  if (tl == 255) cnt[e] = s[255];
  #pragma unroll
  for (int i = 0; i < 8; ++i) {
    if (mem[i]) {
      const int t = base + i;
      tok[e * TT + r] = t;
      posmap[t * NE + e] = r;
      ++r;
    }
  }
}

__global__ void k_cast4(const float4* __restrict__ src, ushort4* __restrict__ dst, int n4) {
  int stride = gridDim.x * blockDim.x;
  for (int i = blockIdx.x * blockDim.x + threadIdx.x; i < n4; i += stride) {
    float4 f = src[i];
    ushort4 o;
    o.x = f2u(f.x); o.y = f2u(f.y); o.z = f2u(f.z); o.w = f2u(f.w);
    dst[i] = o;
  }
}

// w1,v1 -> combined w12[e][8192][HH] bf16, 16-row interleave:
// w12 rows 32j..32j+15 = w1 rows 16j.., rows 32j+16..32j+31 = v1 rows 16j..
__global__ void k_cast12(const float* __restrict__ w1, const float* __restrict__ v1,
                         u16* __restrict__ w12) {
  const long i = (long)blockIdx.x * 256 + threadIdx.x;  // over NE*FF*HH/8
  const int k8 = (int)(i & 255);                        // HH/8 = 256
  const long fe = i >> 8;
  const int f = (int)(fe & (FF - 1));
  const int e = (int)(fe >> 12);
  const size_t so = ((size_t)(e * FF + f)) * HH + (size_t)k8 * 8;
  const int cr = ((f >> 4) << 5) + (f & 15);
  u16* d1 = w12 + ((size_t)e * 2 * FF + cr) * HH + (size_t)k8 * 8;
  u16* d2 = d1 + (size_t)16 * HH;
  float4 a = ((const float4*)(w1 + so))[0];
  float4 b = ((const float4*)(w1 + so))[1];
  ((ushort4*)d1)[0] = (ushort4){f2u(a.x), f2u(a.y), f2u(a.z), f2u(a.w)};
  ((ushort4*)d1)[1] = (ushort4){f2u(b.x), f2u(b.y), f2u(b.z), f2u(b.w)};
  a = ((const float4*)(v1 + so))[0];
  b = ((const float4*)(v1 + so))[1];
  ((ushort4*)d2)[0] = (ushort4){f2u(a.x), f2u(a.y), f2u(a.z), f2u(a.w)};
  ((ushort4*)d2)[1] = (ushort4){f2u(b.x), f2u(b.y), f2u(b.z), f2u(b.w)};
}

// w2[e]: [FF][HH] fp32 -> [HH][FF] bf16 transposed
__global__ void k_tcast(const float* __restrict__ w2, u16* __restrict__ dst) {
  const int e = blockIdx.z;
  const float* src = w2 + (size_t)e * FF * HH;
  u16* d = dst + (size_t)e * HH * FF;
  __shared__ float tile[32][33];
  int h0 = blockIdx.x * 32;
  int f0 = blockIdx.y * 32;
  int tx = threadIdx.x, ty = threadIdx.y;
  #pragma unroll
  for (int i = 0; i < 4; ++i)
    tile[ty + i*8][tx] = src[(size_t)(f0 + ty + i*8) * HH + h0 + tx];
  __syncthreads();
  #pragma unroll
  for (int i = 0; i < 4; ++i)
    d[(size_t)(h0 + ty + i*8) * FF + f0 + tx] = f2u(tile[tx][ty + i*8]);
}

// gather x rows into per-expert panels, zero-pad to 256 multiple.
__global__ void k_gather(const u16* __restrict__ xb, const int* __restrict__ tok,
                         const int* __restrict__ cnt, u16* __restrict__ xg) {
  const int e = blockIdx.y;
  const int r = blockIdx.x;
  const int c = cnt[e];
  const int mcap = (c + 255) & ~255;
  if (r >= mcap) return;
  uint4* dst = (uint4*)(xg + ((size_t)e * TT + r) * HH) + threadIdx.x;
  if (r < c) {
    const uint4* src = (const uint4*)(xb + (size_t)tok[e * TT + r] * HH) + threadIdx.x;
    *dst = *src;
  } else {
    *dst = (uint4){0, 0, 0, 0};
  }
}

// 256x256 pipelined bf16 GEMM, BK=64, 8 waves (2Mx4N), 128KB dbuf LDS,
// counted vmcnt + raw barriers, T2 row-XOR swizzle, T5 setprio.
// MODE 0: GLU  A=xg[e] (K=2048), B=w12[e] (8192 rows), out hc bf16 silu-fused
// MODE 1: down A=hc[e] (K=4096), B=w2t[e] (2048 rows), out dcomp fp32
template<int MODE>
__global__ __launch_bounds__(512)
void gemm256(const u16* __restrict__ Aall, const u16* __restrict__ Ball,
             const int* __restrict__ cnt, void* __restrict__ Oall) {
  constexpr int KD  = (MODE == 0) ? HH : FF;   // 2048 / 4096
  constexpr int NTK = KD / 64;                 // 32 / 64
  constexpr int NT  = (MODE == 0) ? 32 : 8;    // N tiles
  constexpr int NB  = (MODE == 0) ? 2 * FF : HH;

  const int nwg = gridDim.x;
  const int bid = blockIdx.x;
  const int swz = (bid & 7) * (nwg >> 3) + (bid >> 3);
  const int e   = swz / (8 * NT);
  const int rem = swz % (8 * NT);
  const int mt  = rem / NT;
  const int ntl = rem % NT;
  const int c = cnt[e];
  const int mcap = (c + 255) & ~255;
  if (mt * 256 >= mcap) return;

  __shared__ __align__(16) u16 smem[65536];    // 128 KB
  u16* const As0 = smem;
  u16* const As1 = smem + 16384;
  u16* const Bs0 = smem + 32768;
  u16* const Bs1 = smem + 49152;

  const int tid  = threadIdx.x;
  const int lane = tid & 63;
  const int wave = tid >> 6;
  const int wm = wave >> 2;      // 0..1
  const int wn = wave & 3;       // 0..3

  const u16* A = Aall + (size_t)e * TT * KD + (size_t)(mt * 256) * KD;
  const u16* B = Ball + (size_t)e * NB * KD + (size_t)(ntl * 256) * KD;

  // staging: thread covers LDS bytes q = li*8192 + tid*16 (linear dest);
  // logical element = q XOR ((row&7)<<4)  -> pre-swizzled global source col
  const int srow = tid >> 3;                                   // 0..63
  const int scol = (((tid & 7) ^ ((tid >> 3) & 7)) << 3);      // u16 units
  const u16* Asrc0 = A + (size_t)(0 * 64 + srow) * KD + scol;
  const u16* Asrc1 = A + (size_t)(1 * 64 + srow) * KD + scol;
  const u16* Asrc2 = A + (size_t)(2 * 64 + srow) * KD + scol;
  const u16* Asrc3 = A + (size_t)(3 * 64 + srow) * KD + scol;
  const u16* Bsrc0 = B + (size_t)(0 * 64 + srow) * KD + scol;
  const u16* Bsrc1 = B + (size_t)(1 * 64 + srow) * KD + scol;
  const u16* Bsrc2 = B + (size_t)(2 * 64 + srow) * KD + scol;
  const u16* Bsrc3 = B + (size_t)(3 * 64 + srow) * KD + scol;

  auto stage = [&](u16* ad, u16* bd, int kt) {
    const int ko = kt * 64;
    u16* a = ad + tid * 8;
    u16* b = bd + tid * 8;
    gld16(a,            Asrc0 + ko);
    gld16(a + 4096,     Asrc1 + ko);
    gld16(a + 8192,     Asrc2 + ko);
    gld16(a + 12288,    Asrc3 + ko);
    gld16(b,            Bsrc0 + ko);
    gld16(b + 4096,     Bsrc1 + ko);
    gld16(b + 8192,     Bsrc2 + ko);
    gld16(b + 12288,    Bsrc3 + ko);
  };

  f32x4 acc[8][4];
  #pragma unroll
  for (int m = 0; m < 8; ++m)
    #pragma unroll
    for (int n = 0; n < 4; ++n)
      acc[m][n] = (f32x4){0.f, 0.f, 0.f, 0.f};

  const int lr = lane & 15;
  // swizzled col part per ks (u16 units): (ks*32 + (lane>>4)*8) ^ ((lane&7)*8)
  int cs0 = ((0 << 5) + (((lane >> 4) & 3) << 3)) ^ ((lane & 7) << 3);
  int cs1 = ((1 << 5) + (((lane >> 4) & 3) << 3)) ^ ((lane & 7) << 3);

  auto compute = [&](const u16* ab, const u16* bb) {
    __builtin_amdgcn_s_setprio(1);
    #pragma unroll
    for (int ks = 0; ks < 2; ++ks) {
      const int cpp = ks ? cs1 : cs0;
      bf16x8 bf[4];
      #pragma unroll
      for (int n = 0; n < 4; ++n) {
        const int row = wn * 64 + n * 16 + lr;
        bf[n] = *(const bf16x8*)(bb + (row << 6) + cpp);
      }
      #pragma unroll
      for (int m = 0; m < 8; ++m) {
        const int row = wm * 128 + m * 16 + lr;
        bf16x8 af = *(const bf16x8*)(ab + (row << 6) + cpp);
        #pragma unroll
        for (int n = 0; n < 4; ++n)
          acc[m][n] = __builtin_amdgcn_mfma_f32_16x16x32_bf16(af, bf[n], acc[m][n], 0, 0, 0);
      }
    }
    __builtin_amdgcn_s_setprio(0);
  };

  // pipeline: 2 K-tiles in flight, vmcnt(8) = keep next tile's 8 loads pending
  stage(As0, Bs0, 0);
  stage(As1, Bs1, 1);
  for (int t = 0; t < NTK; ++t) {
    if (t == NTK - 1) { asm volatile("s_waitcnt vmcnt(0)" ::: "memory"); }
    else              { asm volatile("s_waitcnt vmcnt(8)" ::: "memory"); }
    __builtin_amdgcn_s_barrier();
    __builtin_amdgcn_sched_barrier(0);
    const int b = t & 1;
    compute(b ? As1 : As0, b ? Bs1 : Bs0);
    __builtin_amdgcn_sched_barrier(0);
    __builtin_amdgcn_s_barrier();
    __builtin_amdgcn_sched_barrier(0);
    if (t + 2 < NTK) stage(b ? As1 : As0, b ? Bs1 : Bs0, t + 2);
  }

  // C/D: col = lane&15, row = (lane>>4)*4 + j  (verified)
  const int rb = mt * 256 + wm * 128 + ((lane >> 4) << 2);
  if (MODE == 0) {
    u16* H = (u16*)Oall + (size_t)e * TT * FF;
    const int fb = ntl * 128 + wn * 32 + lr;
    #pragma unroll
    for (int m = 0; m < 8; ++m)
      #pragma unroll
      for (int np = 0; np < 2; ++np)
        #pragma unroll
        for (int j = 0; j < 4; ++j) {
          float g = acc[m][2*np][j];
          float u = acc[m][2*np + 1][j];
          float hh = (g / (1.f + __expf(-g))) * u;
          H[(size_t)(rb + m*16 + j) * FF + fb + np*16] = f2u(hh);
        }
  } else {
    float* D = (float*)Oall + (size_t)e * TT * HH;
    const int cb = ntl * 256 + wn * 64 + lr;
    #pragma unroll
    for (int m = 0; m < 8; ++m)
      #pragma unroll
      for (int n = 0; n < 4; ++n)
        #pragma unroll
        for (int j = 0; j < 4; ++j)
          D[(size_t)(rb + m*16 + j) * HH + cb + n*16] = acc[m][n][j];
  }
}

__global__ void k_combine(const float* __restrict__ tw, const int* __restrict__ te,
                          const int* __restrict__ posmap, const float* __restrict__ dcomp,
                          float* __restrict__ out) {
  const int t = blockIdx.x;
  const int c0 = threadIdx.x * 8;
  float a[8] = {0.f, 0.f, 0.f, 0.f, 0.f, 0.f, 0.f, 0.f};
  #pragma unroll
  for (int k = 0; k < KTOP; ++k) {
    const int e = te[t * KTOP + k];
    const float w = tw[t * KTOP + k];
    const int r = posmap[t * NE + e];
    const float* row = dcomp + ((size_t)e * TT + r) * HH + c0;
    const float4 p = ((const float4*)row)[0];
    const float4 q = ((const float4*)row)[1];
    a[0] += w * p.x; a[1] += w * p.y; a[2] += w * p.z; a[3] += w * p.w;
    a[4] += w * q.x; a[5] += w * q.y; a[6] += w * q.z; a[7] += w * q.w;
  }
  float* o = out + (size_t)t * HH + c0;
  ((float4*)o)[0] = (float4){a[0], a[1], a[2], a[3]};
  ((float4*)o)[1] = (float4){a[4], a[5], a[6], a[7]};
}

extern "C" void kernel_launch(void* const* d_in, const int* in_sizes, int n_in,
                              void* d_out, int out_size, void* d_ws, size_t ws_size,
                              hipStream_t stream) {
  const float* x  = (const float*)d_in[0];
  const float* tw = (const float*)d_in[2];
  const int*   te = (const int*)d_in[3];
  const float* w1 = (const float*)d_in[4];
  const float* v1 = (const float*)d_in[5];
  const float* w2 = (const float*)d_in[6];
  float* out = (float*)d_out;

  char* p = (char*)d_ws;
  int*   cnt    = (int*)p;   p += 256;
  int*   tok    = (int*)p;   p += (size_t)NE * TT * 4;
  int*   posmap = (int*)p;   p += (size_t)TT * NE * 4;
  u16*   xb     = (u16*)p;   p += (size_t)TT * HH * 2;            // 8 MB
  u16*   xg     = (u16*)p;   p += (size_t)NE * TT * HH * 2;       // 64 MB
  u16*   w12b   = (u16*)p;   p += (size_t)NE * 2 * FF * HH * 2;   // 268 MB
  u16*   w2tb   = (u16*)p;   p += (size_t)NE * HH * FF * 2;       // 134 MB
  u16*   hc     = (u16*)p;   p += (size_t)NE * TT * FF * 2;       // 134 MB
  float* dcomp  = (float*)p; p += (size_t)NE * TT * HH * 4;       // 134 MB

  k_build<<<NE, 256, 0, stream>>>(te, cnt, tok, posmap);
  k_cast4<<<1024, 256, 0, stream>>>((const float4*)x, (ushort4*)xb, TT * HH / 4);
  k_cast12<<<NE * FF * (HH / 8) / 256, 256, 0, stream>>>(w1, v1, w12b);
  k_tcast<<<dim3(HH / 32, FF / 32, NE), dim3(32, 8), 0, stream>>>(w2, w2tb);
  k_gather<<<dim3(TT, NE), 256, 0, stream>>>(xb, tok, cnt, xg);

  // GLU: per expert 8 mtiles x 32 ntiles = 2048 blocks
  gemm256<0><<<2048, 512, 0, stream>>>(xg, w12b, cnt, hc);
  // down: per expert 8 mtiles x 8 ntiles = 512 blocks
  gemm256<1><<<512, 512, 0, stream>>>(hc, w2tb, cnt, dcomp);
  k_combine<<<TT, 256, 0, stream>>>(tw, te, posmap, dcomp, out);
}